// Round 4
// baseline (2018.586 us; speedup 1.0000x reference)
//
#include <hip/hip_runtime.h>
#include <hip/hip_bf16.h>

#define EPS       0.05f
#define N_ITERS   20
#define NR        8192      // N == M
#define DIM       64
#define LOG2E     1.4426950408889634f
#define LN2       0.6931471805599453f
#define S2        (2.0f * LOG2E / EPS)   // 57.7078...
#define EPSLN2    (EPS * LN2)
#define CT        128                    // cols per LDS tile
#define NT        (NR / CT)              // 64 tiles

typedef __attribute__((ext_vector_type(8))) short short8;
typedef __attribute__((ext_vector_type(4))) float float4v;

__device__ __forceinline__ float wave_reduce_sum(float v) {
    #pragma unroll
    for (int m = 1; m < 64; m <<= 1) v += __shfl_xor(v, m, 64);
    return v;
}

// ---- setup: sums of a and b ------------------------------------------------
__global__ void sums_kernel(const float* __restrict__ a, const float* __restrict__ b,
                            float* __restrict__ sums) {
    __shared__ float red[32];
    int tid = threadIdx.x;
    float pa = 0.f, pb = 0.f;
    for (int i = tid; i < NR; i += blockDim.x) { pa += a[i]; pb += b[i]; }
    pa = wave_reduce_sum(pa);
    pb = wave_reduce_sum(pb);
    int wid = tid >> 6, ln = tid & 63;
    if (ln == 0) { red[wid] = pa; red[wid + 16] = pb; }
    __syncthreads();
    if (tid == 0) {
        float sa = 0.f, sb = 0.f;
        int nw = blockDim.x >> 6;
        for (int w = 0; w < nw; w++) { sa += red[w]; sb += red[w + 16]; }
        sums[0] = logf(sa); sums[1] = logf(sb); sums[2] = sa; sums[3] = sb;
    }
}

// ---- setup: bf16 copies, squared norms, log-weights, initial col bias ------
__global__ void prep_kernel(const float* __restrict__ x, const float* __restrict__ y,
                            const float* __restrict__ a, const float* __restrict__ b,
                            const float* __restrict__ sums,
                            __hip_bfloat16* __restrict__ xb, __hip_bfloat16* __restrict__ yb,
                            float* __restrict__ x2, float* __restrict__ y2,
                            float* __restrict__ la2, float* __restrict__ lb2,
                            float* __restrict__ bias_c) {
    int gw = blockIdx.x * (blockDim.x >> 6) + (threadIdx.x >> 6);
    int ln = threadIdx.x & 63;
    bool isx = gw < NR;
    int row = isx ? gw : gw - NR;
    const float* src = isx ? x : y;
    float v = src[row * DIM + ln];
    float sq = wave_reduce_sum(v * v);
    (isx ? xb : yb)[row * DIM + ln] = __float2bfloat16(v);
    if (ln == 0) {
        if (isx) {
            x2[row] = sq;
            la2[row] = (logf(a[row]) - sums[0]) * LOG2E;
        } else {
            y2[row] = sq;
            float lw = (logf(b[row]) - sums[1]) * LOG2E;
            lb2[row] = lw;
            bias_c[row] = lw - sq * (LOG2E / EPS);   // g = 0 initially
        }
    }
}

#define LSE_UPDATE(acc, cbv, mm, ss)                                  \
    {                                                                 \
        float z = fmaf(S2, (acc), (cbv));                             \
        float t = z - (mm);                                           \
        float e = __builtin_amdgcn_exp2f(-fabsf(t));                  \
        bool  gg = z > (mm);                                          \
        (mm) = fmaxf((mm), z);                                        \
        (ss) = fmaf((ss), gg ? e : 1.0f, gg ? 1.0f : e);              \
    }

// ---- one softmin sweep -----------------------------------------------------
// R4: B streamed through double-buffered LDS via async global_load_lds
// (16B/lane), XOR-swizzled so ds_read_b128 fragment fetches are ~conflict-free.
// Block: 1024 thr = 16 waves; 32 rows per block; 64 tiles of 128 cols.
// Wave w: row-tile rt=w>>3 (16 rows), col-slice ct=w&7 (16 of the 128 cols).
//
// LDS tile layout: local B-row r (=col j - tile*128, 0..127) is 128 B;
// 16 B chunk slot p holds logical k-chunk c = p ^ (r&7).
__global__ __launch_bounds__(1024) void pass_kernel(
        const __hip_bfloat16* __restrict__ matA,   // [8192][64] bf16, row side
        const __hip_bfloat16* __restrict__ matB,   // [8192][64] bf16, col side
        const float* __restrict__ bias_in,         // [8192] log2-domain col bias
        const float* __restrict__ sq_row,          // [8192]
        const float* __restrict__ lw2_row,         // [8192]
        float* __restrict__ pot_out,               // [8192]
        float* __restrict__ bias_out) {            // [8192]
    __shared__ __attribute__((aligned(16))) char bstage[2][16384];
    __shared__ float2 comb[32][8];

    const int tid  = threadIdx.x;
    const int w    = tid >> 6;        // wave 0..15
    const int lane = tid & 63;
    const int q    = lane >> 4;       // k-quad
    const int ln   = lane & 15;       // row (A) / col (B) within 16-tile
    const int rt   = w >> 3;          // row-tile 0..1
    const int ct   = w & 7;           // col-slice 0..7
    const int rb   = blockIdx.x * 32;

    // A fragments (resident): rows rb + rt*16 + ln, k-chunks q and q+4
    const short8* A8 = (const short8*)matA;
    const int arow = rb + rt * 16 + ln;
    short8 a0 = A8[arow * 8 + q];
    short8 a1 = A8[arow * 8 + q + 4];

    // staging address pattern for this thread (covers local row 8w+(lane>>3))
    const int srow   = 8 * w + (lane >> 3);          // local B-row 0..127
    const int schunk = (lane & 7) ^ (lane >> 3);     // logical chunk to fetch
    const char* gB = (const char*)matB;

    // ds_read address for this lane's fragment: local row ct*16+ln, chunk q
    const int rdoff = (ct * 16 + ln) * 128 + ((q ^ (ln & 7)) * 16);

    float m0[4], s0[4];
    #pragma unroll
    for (int r = 0; r < 4; r++) { m0[r] = -1e30f; s0[r] = 0.f; }

    // prologue: stage tile 0 into buf 0, prefetch its bias
    __builtin_amdgcn_global_load_lds(
        (const __attribute__((address_space(1))) void*)
            (gB + (size_t)(0 * CT + srow) * 128 + schunk * 16),
        (__attribute__((address_space(3))) void*)(&bstage[0][w * 1024]),
        16, 0, 0);
    float cb = bias_in[ct * 16 + ln];
    __syncthreads();   // tile 0 staged

    for (int t = 0; t < NT; t++) {
        const int cur = t & 1;
        // async-stage tile t+1 into the other buffer (readers of it finished
        // at the barrier ending iter t-1)
        if (t + 1 < NT) {
            __builtin_amdgcn_global_load_lds(
                (const __attribute__((address_space(1))) void*)
                    (gB + (size_t)((t + 1) * CT + srow) * 128 + schunk * 16),
                (__attribute__((address_space(3))) void*)(&bstage[1 - cur][w * 1024]),
                16, 0, 0);
        }
        float ncb = (t + 1 < NT) ? bias_in[(t + 1) * CT + ct * 16 + ln] : 0.f;

        // fragments from LDS (swizzled): chunk q and q+4 of local row ct*16+ln
        const char* base = &bstage[cur][0];
        short8 b0 = *(const short8*)(base + rdoff);
        short8 b1 = *(const short8*)(base + (rdoff ^ 64));

        float4v acc = {0.f, 0.f, 0.f, 0.f};
        acc = __builtin_amdgcn_mfma_f32_16x16x32_bf16(a0, b0, acc, 0, 0, 0);
        acc = __builtin_amdgcn_mfma_f32_16x16x32_bf16(a1, b1, acc, 0, 0, 0);

        #pragma unroll
        for (int r = 0; r < 4; r++) LSE_UPDATE(acc[r], cb, m0[r], s0[r]);

        cb = ncb;
        __syncthreads();   // drains stage(t+1); protects buf reuse
    }

    // combine across the 16 lanes (ln) sharing the same rows
    #pragma unroll
    for (int mask = 1; mask < 16; mask <<= 1) {
        #pragma unroll
        for (int r = 0; r < 4; r++) {
            float mo = __shfl_xor(m0[r], mask, 64);
            float so = __shfl_xor(s0[r], mask, 64);
            float M  = fmaxf(m0[r], mo);
            s0[r] = s0[r] * __builtin_amdgcn_exp2f(m0[r] - M)
                  + so    * __builtin_amdgcn_exp2f(mo    - M);
            m0[r] = M;
        }
    }

    if (ln == 0) {   // lanes 0,16,32,48: rows rt*16 + q*4 + r
        #pragma unroll
        for (int r = 0; r < 4; r++)
            comb[rt * 16 + q * 4 + r][ct] = make_float2(m0[r], s0[r]);
    }
    __syncthreads();

    // merge the 8 col-slices per row and write outputs
    if (tid < 32) {
        float M = -1e30f;
        #pragma unroll
        for (int c = 0; c < 8; c++) M = fmaxf(M, comb[tid][c].x);
        float S = 0.f;
        #pragma unroll
        for (int c = 0; c < 8; c++) {
            float2 p = comb[tid][c];
            S += p.y * __builtin_amdgcn_exp2f(p.x - M);
        }
        float L = M + __builtin_amdgcn_logf(S);   // log2-domain LSE
        int row = rb + tid;
        pot_out[row]  = sq_row[row] - EPSLN2 * L;
        bias_out[row] = lw2_row[row] - L;
    }
}

// ---- final reduction: <a,f_fin>/sum_a + <b,g_fin>/sum_b --------------------
__global__ void reduce_kernel(const float* __restrict__ a, const float* __restrict__ b,
                              const float* __restrict__ sums,
                              const float* __restrict__ ffin, const float* __restrict__ gfin,
                              float* __restrict__ out) {
    __shared__ float red[32];
    int tid = threadIdx.x;
    float da = 0.f, db = 0.f;
    for (int i = tid; i < NR; i += blockDim.x) { da += a[i] * ffin[i]; db += b[i] * gfin[i]; }
    da = wave_reduce_sum(da);
    db = wave_reduce_sum(db);
    int wid = tid >> 6, ln = tid & 63;
    if (ln == 0) { red[wid] = da; red[wid + 16] = db; }
    __syncthreads();
    if (tid == 0) {
        float DA = 0.f, DB = 0.f;
        int nw = blockDim.x >> 6;
        for (int w = 0; w < nw; w++) { DA += red[w]; DB += red[w + 16]; }
        out[0] = DA / sums[2] + DB / sums[3];
    }
}

extern "C" void kernel_launch(void* const* d_in, const int* in_sizes, int n_in,
                              void* d_out, int out_size, void* d_ws, size_t ws_size,
                              hipStream_t stream) {
    const float* a = (const float*)d_in[0];
    const float* x = (const float*)d_in[1];
    const float* b = (const float*)d_in[2];
    const float* y = (const float*)d_in[3];

    char* ws = (char*)d_ws;
    __hip_bfloat16* xb = (__hip_bfloat16*)ws;                      // 1 MB
    __hip_bfloat16* yb = (__hip_bfloat16*)(ws + (1 << 20));        // 1 MB
    float* fp       = (float*)(ws + (2 << 20));
    float* x2       = fp + 0 * NR;
    float* y2       = fp + 1 * NR;
    float* la2      = fp + 2 * NR;
    float* lb2      = fp + 3 * NR;
    float* bias_c   = fp + 4 * NR;
    float* bias_r   = fp + 5 * NR;
    float* bias_jnk = fp + 6 * NR;
    float* f        = fp + 7 * NR;
    float* g        = fp + 8 * NR;
    float* f_fin    = fp + 9 * NR;
    float* g_fin    = fp + 10 * NR;
    float* sums     = fp + 11 * NR;

    sums_kernel<<<1, 1024, 0, stream>>>(a, b, sums);
    prep_kernel<<<(2 * NR) / 4, 256, 0, stream>>>(x, y, a, b, sums,
                                                  xb, yb, x2, y2, la2, lb2, bias_c);

    for (int it = 0; it < N_ITERS; it++) {
        // f = softmin_rows(g): uses bias_c (from g), emits bias_r (from new f)
        pass_kernel<<<256, 1024, 0, stream>>>(xb, yb, bias_c, x2, la2, f, bias_r);
        // g = softmin_cols(f): uses bias_r, emits bias_c
        pass_kernel<<<256, 1024, 0, stream>>>(yb, xb, bias_r, y2, lb2, g, bias_c);
    }
    // final symmetric update from detached potentials:
    // f_fin from g20 (bias_c), g_fin from f20 (bias_r — must not be clobbered)
    pass_kernel<<<256, 1024, 0, stream>>>(xb, yb, bias_c, x2, la2, f_fin, bias_jnk);
    pass_kernel<<<256, 1024, 0, stream>>>(yb, xb, bias_r, y2, lb2, g_fin, bias_jnk);

    reduce_kernel<<<1, 1024, 0, stream>>>(a, b, sums, f_fin, g_fin, (float*)d_out);
}

// Round 5
// 1559.307 us; speedup vs baseline: 1.2945x; 1.2945x over previous
//
#include <hip/hip_runtime.h>
#include <hip/hip_bf16.h>

#define EPS       0.05f
#define N_ITERS   20
#define NR        8192      // N == M
#define DIM       64
#define LOG2E     1.4426950408889634f
#define LN2       0.6931471805599453f
#define S2        (2.0f * LOG2E / EPS)   // 57.7078...
#define EPSLN2    (EPS * LN2)
#define NEGINF    (-1e30f)

typedef __attribute__((ext_vector_type(8))) short short8;
typedef __attribute__((ext_vector_type(4))) float float4v;

__device__ __forceinline__ float wave_reduce_sum(float v) {
    #pragma unroll
    for (int m = 1; m < 64; m <<= 1) v += __shfl_xor(v, m, 64);
    return v;
}

// merged log2-LSE of two partials
__device__ __forceinline__ float merge_l(float m0, float s0, float m1, float s1) {
    float M = fmaxf(m0, m1);
    float S = s0 * __builtin_amdgcn_exp2f(m0 - M) + s1 * __builtin_amdgcn_exp2f(m1 - M);
    return M + __builtin_amdgcn_logf(S);   // log2
}

// ---- setup: sums of a and b ------------------------------------------------
__global__ void sums_kernel(const float* __restrict__ a, const float* __restrict__ b,
                            float* __restrict__ sums) {
    __shared__ float red[32];
    int tid = threadIdx.x;
    float pa = 0.f, pb = 0.f;
    for (int i = tid; i < NR; i += blockDim.x) { pa += a[i]; pb += b[i]; }
    pa = wave_reduce_sum(pa);
    pb = wave_reduce_sum(pb);
    int wid = tid >> 6, ln = tid & 63;
    if (ln == 0) { red[wid] = pa; red[wid + 16] = pb; }
    __syncthreads();
    if (tid == 0) {
        float sa = 0.f, sb = 0.f;
        int nw = blockDim.x >> 6;
        for (int w = 0; w < nw; w++) { sa += red[w]; sb += red[w + 16]; }
        sums[0] = logf(sa); sums[1] = logf(sb); sums[2] = sa; sums[3] = sb;
    }
}

// ---- setup: bf16 copies, norms, log-weights, initial column partials -------
// one wave per row; lane k handles element k (DIM == 64)
__global__ void prep_kernel(const float* __restrict__ x, const float* __restrict__ y,
                            const float* __restrict__ a, const float* __restrict__ b,
                            const float* __restrict__ sums,
                            __hip_bfloat16* __restrict__ xb, __hip_bfloat16* __restrict__ yb,
                            float* __restrict__ x2, float* __restrict__ y2,
                            float* __restrict__ la2, float* __restrict__ lb2,
                            float2* __restrict__ Pb) {   // [2][NR] initial g-partials
    int gw = blockIdx.x * (blockDim.x >> 6) + (threadIdx.x >> 6);
    int ln = threadIdx.x & 63;
    bool isx = gw < NR;
    int row = isx ? gw : gw - NR;
    const float* src = isx ? x : y;
    float v = src[row * DIM + ln];
    float sq = wave_reduce_sum(v * v);
    (isx ? xb : yb)[row * DIM + ln] = __float2bfloat16(v);
    if (ln == 0) {
        if (isx) {
            x2[row] = sq;
            la2[row] = (logf(a[row]) - sums[0]) * LOG2E;
        } else {
            y2[row] = sq;
            lb2[row] = (logf(b[row]) - sums[1]) * LOG2E;
            // g = 0 initially: bias_j = lb2_j - L_j with L_j = y2_j*LOG2E/EPS
            Pb[row]      = make_float2(sq * (LOG2E / EPS), 1.0f);
            Pb[NR + row] = make_float2(NEGINF, 0.0f);
        }
    }
}

// 4-wide online LSE update: one state, 4 new z's
#define LSE4(acc, c4, mm, ss)                                            \
    {                                                                    \
        float z0 = fmaf(S2, (acc)[0], (c4).x);                           \
        float z1 = fmaf(S2, (acc)[1], (c4).y);                           \
        float z2 = fmaf(S2, (acc)[2], (c4).z);                           \
        float z3 = fmaf(S2, (acc)[3], (c4).w);                           \
        float zm = fmaxf(fmaxf(z0, z1), fmaxf(z2, z3));                  \
        float mn = fmaxf((mm), zm);                                      \
        float e  = __builtin_amdgcn_exp2f((mm) - mn);                    \
        float p  = (__builtin_amdgcn_exp2f(z0 - mn)                      \
                  + __builtin_amdgcn_exp2f(z1 - mn))                     \
                 + (__builtin_amdgcn_exp2f(z2 - mn)                      \
                  + __builtin_amdgcn_exp2f(z3 - mn));                    \
        (ss) = fmaf((ss), e, p);                                         \
        (mm) = mn;                                                       \
    }

// ---- one softmin sweep (half of the columns) -------------------------------
// Computes, for 32 output rows i and 4096 columns j (half h):
//   partial (M,S) of LSE2_j( cb_j + S2*<X_i, Y_j> ),
//   cb_j = lw2col_j - merge(Pin[0][j], Pin[1][j])   (prologue, LDS-cached)
// Operand-swapped MFMA: A = Y (streamed), B = X (resident) so each lane's
// 4 acc regs are 4 columns of ONE output row -> single (m,s) state/lane/tile.
// Grid: 512 blocks (256 row-groups x 2 halves), 1024 thr = 16 waves.
// Wave w covers cols h*4096 + w*256 .. +256 (16 iters of 16 cols).
__global__ __launch_bounds__(1024, 8) void pass_kernel(
        const __hip_bfloat16* __restrict__ matX,   // [NR][64] resident (rows)
        const __hip_bfloat16* __restrict__ matY,   // [NR][64] streamed (cols)
        const float2* __restrict__ Pin,            // [2][NR] column-side partials
        const float* __restrict__ lw2col,          // [NR]
        float2* __restrict__ Pout) {               // [2][NR] row-side partials
    __shared__ __attribute__((aligned(16))) float cbl[4096];
    __shared__ float2 comb[32][16];

    const int tid = threadIdx.x;
    const int bi  = blockIdx.x;
    const int h   = bi & 1;
    const int rb  = (bi >> 1) * 32;
    const int cb0 = h * 4096;

    // ---- prologue: merge column partials -> cb for this block's 4096 cols
    {
        int j = cb0 + tid * 4;
        const float4* P0 = (const float4*)(Pin + j);        // half-0 pairs
        const float4* P1 = (const float4*)(Pin + NR + j);   // half-1 pairs
        float4 q0 = P0[0], q1 = P0[1];
        float4 r0 = P1[0], r1 = P1[1];
        float4 lw = *(const float4*)(lw2col + j);
        float4 cb;
        cb.x = lw.x - merge_l(q0.x, q0.y, r0.x, r0.y);
        cb.y = lw.y - merge_l(q0.z, q0.w, r0.z, r0.w);
        cb.z = lw.z - merge_l(q1.x, q1.y, r1.x, r1.y);
        cb.w = lw.w - merge_l(q1.z, q1.w, r1.z, r1.w);
        *(float4*)(cbl + tid * 4) = cb;
    }

    const int w    = tid >> 6;        // wave 0..15
    const int lane = tid & 63;
    const int quad = lane >> 4;
    const int ln   = lane & 15;

    // resident X fragments (B-operand): rows rb+ln and rb+16+ln, k-chunks quad/quad+4
    const short8* X8 = (const short8*)matX;
    short8 xb0 = X8[(rb + ln) * 8 + quad];
    short8 xb1 = X8[(rb + ln) * 8 + quad + 4];
    short8 xb2 = X8[(rb + 16 + ln) * 8 + quad];
    short8 xb3 = X8[(rb + 16 + ln) * 8 + quad + 4];

    // streamed Y pointer (A-operand): rows cb0 + w*256 + jt*16 + ln
    const short8* yp = (const short8*)matY + (size_t)(cb0 + w * 256 + ln) * 8 + quad;
    const float4* cbw = (const float4*)(cbl + w * 256) + quad;

    float m0 = NEGINF, s0 = 0.f, m1 = NEGINF, s1 = 0.f;

    __syncthreads();   // cbl ready

    #pragma unroll 4
    for (int jt = 0; jt < 16; jt++) {
        short8 ya0 = yp[0];
        short8 ya1 = yp[4];
        float4 c4  = cbw[jt * 4];
        yp += 128;   // 16 rows * 8 chunks

        float4v acc0 = {0.f, 0.f, 0.f, 0.f};
        float4v acc1 = {0.f, 0.f, 0.f, 0.f};
        acc0 = __builtin_amdgcn_mfma_f32_16x16x32_bf16(ya0, xb0, acc0, 0, 0, 0);
        acc0 = __builtin_amdgcn_mfma_f32_16x16x32_bf16(ya1, xb1, acc0, 0, 0, 0);
        acc1 = __builtin_amdgcn_mfma_f32_16x16x32_bf16(ya0, xb2, acc1, 0, 0, 0);
        acc1 = __builtin_amdgcn_mfma_f32_16x16x32_bf16(ya1, xb3, acc1, 0, 0, 0);

        LSE4(acc0, c4, m0, s0);   // row rb + ln
        LSE4(acc1, c4, m1, s1);   // row rb + 16 + ln
    }

    // combine across the 4 quads (same ln = same output rows)
    #pragma unroll
    for (int mask = 16; mask < 64; mask <<= 1) {
        float mo = __shfl_xor(m0, mask, 64);
        float so = __shfl_xor(s0, mask, 64);
        float M  = fmaxf(m0, mo);
        s0 = s0 * __builtin_amdgcn_exp2f(m0 - M) + so * __builtin_amdgcn_exp2f(mo - M);
        m0 = M;
        mo = __shfl_xor(m1, mask, 64);
        so = __shfl_xor(s1, mask, 64);
        M  = fmaxf(m1, mo);
        s1 = s1 * __builtin_amdgcn_exp2f(m1 - M) + so * __builtin_amdgcn_exp2f(mo - M);
        m1 = M;
    }

    if (lane < 16) {
        comb[ln][w]      = make_float2(m0, s0);
        comb[16 + ln][w] = make_float2(m1, s1);
    }
    __syncthreads();

    // merge the 16 wave-strips per row; write this half's partial
    if (tid < 32) {
        float2 c = comb[tid][0];
        float M = c.x, S = c.y;
        #pragma unroll
        for (int cc = 1; cc < 16; cc++) {
            float2 p = comb[tid][cc];
            float Mn = fmaxf(M, p.x);
            S = S * __builtin_amdgcn_exp2f(M - Mn)
              + p.y * __builtin_amdgcn_exp2f(p.x - Mn);
            M = Mn;
        }
        Pout[h * NR + rb + tid] = make_float2(M, S);
    }
}

// ---- final reduction: <a, f_fin>/sa + <b, g_fin>/sb ------------------------
__global__ void reduce_kernel(const float* __restrict__ a, const float* __restrict__ b,
                              const float* __restrict__ sums,
                              const float* __restrict__ x2, const float* __restrict__ y2,
                              const float2* __restrict__ Pff, const float2* __restrict__ Pgf,
                              float* __restrict__ out) {
    __shared__ float red[32];
    int tid = threadIdx.x;
    float da = 0.f, db = 0.f;
    for (int i = tid; i < NR; i += blockDim.x) {
        float2 f0 = Pff[i], f1 = Pff[NR + i];
        float2 g0 = Pgf[i], g1 = Pgf[NR + i];
        float fv = x2[i] - EPSLN2 * merge_l(f0.x, f0.y, f1.x, f1.y);
        float gv = y2[i] - EPSLN2 * merge_l(g0.x, g0.y, g1.x, g1.y);
        da += a[i] * fv;
        db += b[i] * gv;
    }
    da = wave_reduce_sum(da);
    db = wave_reduce_sum(db);
    int wid = tid >> 6, ln = tid & 63;
    if (ln == 0) { red[wid] = da; red[wid + 16] = db; }
    __syncthreads();
    if (tid == 0) {
        float DA = 0.f, DB = 0.f;
        int nw = blockDim.x >> 6;
        for (int w = 0; w < nw; w++) { DA += red[w]; DB += red[w + 16]; }
        out[0] = DA / sums[2] + DB / sums[3];
    }
}

extern "C" void kernel_launch(void* const* d_in, const int* in_sizes, int n_in,
                              void* d_out, int out_size, void* d_ws, size_t ws_size,
                              hipStream_t stream) {
    const float* a = (const float*)d_in[0];
    const float* x = (const float*)d_in[1];
    const float* b = (const float*)d_in[2];
    const float* y = (const float*)d_in[3];

    char* ws = (char*)d_ws;
    __hip_bfloat16* xb = (__hip_bfloat16*)ws;                      // 1 MB
    __hip_bfloat16* yb = (__hip_bfloat16*)(ws + (1 << 20));        // 1 MB
    float* fp  = (float*)(ws + (2 << 20));
    float* x2  = fp;
    float* y2  = fp + NR;
    float* la2 = fp + 2 * NR;
    float* lb2 = fp + 3 * NR;
    float2* P   = (float2*)(fp + 4 * NR);
    float2* Pf  = P;                 // f-side partials [2][NR]
    float2* Pb  = P + 2 * NR;        // g-side partials [2][NR]
    float2* Pff = P + 4 * NR;        // final f partials
    float2* Pgf = P + 6 * NR;        // final g partials
    float* sums = (float*)(P + 8 * NR);

    sums_kernel<<<1, 1024, 0, stream>>>(a, b, sums);
    prep_kernel<<<(2 * NR) / 4, 256, 0, stream>>>(x, y, a, b, sums,
                                                  xb, yb, x2, y2, la2, lb2, Pb);

    for (int it = 0; it < N_ITERS; it++) {
        // f-update: rows = x-side, cols = y-side biased by g-partials
        pass_kernel<<<512, 1024, 0, stream>>>(xb, yb, Pb, lb2, Pf);
        // g-update: rows = y-side, cols = x-side biased by f-partials
        pass_kernel<<<512, 1024, 0, stream>>>(yb, xb, Pf, la2, Pb);
    }
    // final symmetric update from detached potentials:
    // f_fin from g20 (Pb), g_fin from f20 (Pf — preserved, fin writes elsewhere)
    pass_kernel<<<512, 1024, 0, stream>>>(xb, yb, Pb, lb2, Pff);
    pass_kernel<<<512, 1024, 0, stream>>>(yb, xb, Pf, la2, Pgf);

    reduce_kernel<<<1, 1024, 0, stream>>>(a, b, sums, x2, y2, Pff, Pgf, (float*)d_out);
}

// Round 6
// 924.434 us; speedup vs baseline: 2.1836x; 1.6868x over previous
//
#include <hip/hip_runtime.h>
#include <hip/hip_bf16.h>

#define EPS       0.05f
#define N_ITERS   20
#define NR        8192      // N == M
#define DIM       64
#define LOG2E     1.4426950408889634f
#define LN2       0.6931471805599453f
#define S2        (2.0f * LOG2E / EPS)   // 57.7078...
#define EPSLN2    (EPS * LN2)
#define NEGINF    (-1e30f)

typedef __attribute__((ext_vector_type(8))) short short8;
typedef __attribute__((ext_vector_type(4))) float float4v;

__device__ __forceinline__ float wave_reduce_sum(float v) {
    #pragma unroll
    for (int m = 1; m < 64; m <<= 1) v += __shfl_xor(v, m, 64);
    return v;
}

// merged log2-LSE of two partials
__device__ __forceinline__ float merge_l(float m0, float s0, float m1, float s1) {
    float M = fmaxf(m0, m1);
    float S = s0 * __builtin_amdgcn_exp2f(m0 - M) + s1 * __builtin_amdgcn_exp2f(m1 - M);
    return M + __builtin_amdgcn_logf(S);   // log2
}

// ---- setup: sums of a and b ------------------------------------------------
__global__ void sums_kernel(const float* __restrict__ a, const float* __restrict__ b,
                            float* __restrict__ sums) {
    __shared__ float red[32];
    int tid = threadIdx.x;
    float pa = 0.f, pb = 0.f;
    for (int i = tid; i < NR; i += blockDim.x) { pa += a[i]; pb += b[i]; }
    pa = wave_reduce_sum(pa);
    pb = wave_reduce_sum(pb);
    int wid = tid >> 6, ln = tid & 63;
    if (ln == 0) { red[wid] = pa; red[wid + 16] = pb; }
    __syncthreads();
    if (tid == 0) {
        float sa = 0.f, sb = 0.f;
        int nw = blockDim.x >> 6;
        for (int w = 0; w < nw; w++) { sa += red[w]; sb += red[w + 16]; }
        sums[0] = logf(sa); sums[1] = logf(sb); sums[2] = sa; sums[3] = sb;
    }
}

// ---- setup: bf16 copies (row-major + MFMA-stream layout), norms, weights ---
// thread = one 16B chunk: cid = row*8 + c  (c = k-chunk 0..7)
// Stream layout (per 16-col tile T): frag f (0/1), slot = lane = quad*16+ln,
//   holds rows T*16+ln, k = f*32 + quad*8 .. +8 -> contiguous 1KB per frag.
__global__ void prep_kernel(const float* __restrict__ x, const float* __restrict__ y,
                            const float* __restrict__ a, const float* __restrict__ b,
                            const float* __restrict__ sums,
                            short8* __restrict__ xr, short8* __restrict__ yr,
                            short8* __restrict__ xs, short8* __restrict__ ys,
                            float* __restrict__ x2, float* __restrict__ y2,
                            float* __restrict__ la2, float* __restrict__ lb2,
                            float2* __restrict__ Pb) {   // [2][NR] initial g-partials
    int gid = blockIdx.x * 256 + threadIdx.x;
    bool isx = gid < NR * 8;
    int cid = isx ? gid : gid - NR * 8;
    int row = cid >> 3;
    int c   = cid & 7;
    const float4* src = (const float4*)(isx ? x : y);
    float4 v0 = src[row * 16 + c * 2];
    float4 v1 = src[row * 16 + c * 2 + 1];

    short8 st;
    st[0] = __bfloat16_as_short(__float2bfloat16(v0.x));
    st[1] = __bfloat16_as_short(__float2bfloat16(v0.y));
    st[2] = __bfloat16_as_short(__float2bfloat16(v0.z));
    st[3] = __bfloat16_as_short(__float2bfloat16(v0.w));
    st[4] = __bfloat16_as_short(__float2bfloat16(v1.x));
    st[5] = __bfloat16_as_short(__float2bfloat16(v1.y));
    st[6] = __bfloat16_as_short(__float2bfloat16(v1.z));
    st[7] = __bfloat16_as_short(__float2bfloat16(v1.w));

    (isx ? xr : yr)[row * 8 + c] = st;                       // row-major
    int T = row >> 4, ln = row & 15, f = c >> 2, q = c & 3;
    (isx ? xs : ys)[T * 128 + f * 64 + q * 16 + ln] = st;    // stream layout

    float sq = v0.x*v0.x + v0.y*v0.y + v0.z*v0.z + v0.w*v0.w
             + v1.x*v1.x + v1.y*v1.y + v1.z*v1.z + v1.w*v1.w;
    #pragma unroll
    for (int m = 1; m < 8; m <<= 1) sq += __shfl_xor(sq, m, 64);

    if (c == 0) {
        if (isx) {
            x2[row] = sq;
            la2[row] = (logf(a[row]) - sums[0]) * LOG2E;
        } else {
            y2[row] = sq;
            lb2[row] = (logf(b[row]) - sums[1]) * LOG2E;
            Pb[row]      = make_float2(sq * (LOG2E / EPS), 1.0f);
            Pb[NR + row] = make_float2(NEGINF, 0.0f);
        }
    }
}

// 4-wide online LSE update: one state, 4 new z's
#define LSE4(acc, c4, mm, ss)                                            \
    {                                                                    \
        float z0 = fmaf(S2, (acc)[0], (c4).x);                           \
        float z1 = fmaf(S2, (acc)[1], (c4).y);                           \
        float z2 = fmaf(S2, (acc)[2], (c4).z);                           \
        float z3 = fmaf(S2, (acc)[3], (c4).w);                           \
        float zm = fmaxf(fmaxf(z0, z1), fmaxf(z2, z3));                  \
        float mn = fmaxf((mm), zm);                                      \
        float e  = __builtin_amdgcn_exp2f((mm) - mn);                    \
        float p  = (__builtin_amdgcn_exp2f(z0 - mn)                      \
                  + __builtin_amdgcn_exp2f(z1 - mn))                     \
                 + (__builtin_amdgcn_exp2f(z2 - mn)                      \
                  + __builtin_amdgcn_exp2f(z3 - mn));                    \
        (ss) = fmaf((ss), e, p);                                         \
        (mm) = mn;                                                       \
    }

// ---- one softmin sweep (half of the columns) -------------------------------
// R6: 64 rows/block (2x Y-reuse vs R5) + Y read from contiguous stream layout
// (one fully-coalesced 1KB wave-load per fragment).
// Grid: 256 blocks = 128 row-groups x 2 col-halves. 1024 thr = 16 waves.
// Wave w: cols h*4096 + w*256 .. +256 (16 tiles of 16).
__global__ __launch_bounds__(1024, 4) void pass_kernel(
        const short8* __restrict__ matXr,   // row-major resident (rows)
        const short8* __restrict__ matYs,   // stream-layout streamed (cols)
        const float2* __restrict__ Pin,     // [2][NR] column-side partials
        const float* __restrict__ lw2col,   // [NR]
        float2* __restrict__ Pout) {        // [2][NR] row-side partials
    __shared__ __attribute__((aligned(16))) float cbl[4096];
    __shared__ float2 comb[64][16];

    const int tid = threadIdx.x;
    const int bi  = blockIdx.x;
    const int h   = bi & 1;
    const int rb  = (bi >> 1) * 64;
    const int cb0 = h * 4096;

    // ---- prologue: merge column partials -> cb for this block's 4096 cols
    {
        int j = cb0 + tid * 4;
        const float4* P0 = (const float4*)(Pin + j);
        const float4* P1 = (const float4*)(Pin + NR + j);
        float4 q0 = P0[0], q1 = P0[1];
        float4 r0 = P1[0], r1 = P1[1];
        float4 lw = *(const float4*)(lw2col + j);
        float4 cb;
        cb.x = lw.x - merge_l(q0.x, q0.y, r0.x, r0.y);
        cb.y = lw.y - merge_l(q0.z, q0.w, r0.z, r0.w);
        cb.z = lw.z - merge_l(q1.x, q1.y, r1.x, r1.y);
        cb.w = lw.w - merge_l(q1.z, q1.w, r1.z, r1.w);
        *(float4*)(cbl + tid * 4) = cb;
    }

    const int w    = tid >> 6;        // wave 0..15
    const int lane = tid & 63;
    const int quad = lane >> 4;
    const int ln   = lane & 15;

    // resident X fragments (B-operand): 4 row-tiles, rows rb + t*16 + ln
    short8 xf0[4], xf1[4];
    #pragma unroll
    for (int t = 0; t < 4; t++) {
        xf0[t] = matXr[(rb + t * 16 + ln) * 8 + quad];
        xf1[t] = matXr[(rb + t * 16 + ln) * 8 + quad + 4];
    }

    // streamed Y (A-operand) from stream layout: tile T, frag f at
    // matYs[T*128 + f*64 + lane] — contiguous 1KB per wave-load.
    const int T0 = h * 256 + w * 16;
    const short8* yp = matYs + (size_t)T0 * 128 + lane;

    float m[4], s[4];
    #pragma unroll
    for (int t = 0; t < 4; t++) { m[t] = NEGINF; s[t] = 0.f; }

    __syncthreads();   // cbl ready

    #pragma unroll 2
    for (int jt = 0; jt < 16; jt++) {
        short8 ya0 = yp[0];
        short8 ya1 = yp[64];
        float4 c4  = *(const float4*)(cbl + (w * 16 + jt) * 16 + quad * 4);
        yp += 128;

        float4v acc[4];
        #pragma unroll
        for (int t = 0; t < 4; t++) {
            float4v z = {0.f, 0.f, 0.f, 0.f};
            z = __builtin_amdgcn_mfma_f32_16x16x32_bf16(ya0, xf0[t], z, 0, 0, 0);
            z = __builtin_amdgcn_mfma_f32_16x16x32_bf16(ya1, xf1[t], z, 0, 0, 0);
            acc[t] = z;
        }
        #pragma unroll
        for (int t = 0; t < 4; t++) LSE4(acc[t], c4, m[t], s[t]);
    }

    // combine across the 4 quads (same ln = same output rows)
    #pragma unroll
    for (int mask = 16; mask < 64; mask <<= 1) {
        #pragma unroll
        for (int t = 0; t < 4; t++) {
            float mo = __shfl_xor(m[t], mask, 64);
            float so = __shfl_xor(s[t], mask, 64);
            float M  = fmaxf(m[t], mo);
            s[t] = s[t] * __builtin_amdgcn_exp2f(m[t] - M)
                 + so   * __builtin_amdgcn_exp2f(mo   - M);
            m[t] = M;
        }
    }

    if (lane < 16) {
        #pragma unroll
        for (int t = 0; t < 4; t++)
            comb[t * 16 + ln][w] = make_float2(m[t], s[t]);
    }
    __syncthreads();

    // merge the 16 wave-strips per row; write this half's partial
    if (tid < 64) {
        float2 c = comb[tid][0];
        float M = c.x, S = c.y;
        #pragma unroll
        for (int cc = 1; cc < 16; cc++) {
            float2 p = comb[tid][cc];
            float Mn = fmaxf(M, p.x);
            S = S * __builtin_amdgcn_exp2f(M - Mn)
              + p.y * __builtin_amdgcn_exp2f(p.x - Mn);
            M = Mn;
        }
        Pout[h * NR + rb + tid] = make_float2(M, S);
    }
}

// ---- final reduction: <a, f_fin>/sa + <b, g_fin>/sb ------------------------
__global__ void reduce_kernel(const float* __restrict__ a, const float* __restrict__ b,
                              const float* __restrict__ sums,
                              const float* __restrict__ x2, const float* __restrict__ y2,
                              const float2* __restrict__ Pff, const float2* __restrict__ Pgf,
                              float* __restrict__ out) {
    __shared__ float red[32];
    int tid = threadIdx.x;
    float da = 0.f, db = 0.f;
    for (int i = tid; i < NR; i += blockDim.x) {
        float2 f0 = Pff[i], f1 = Pff[NR + i];
        float2 g0 = Pgf[i], g1 = Pgf[NR + i];
        float fv = x2[i] - EPSLN2 * merge_l(f0.x, f0.y, f1.x, f1.y);
        float gv = y2[i] - EPSLN2 * merge_l(g0.x, g0.y, g1.x, g1.y);
        da += a[i] * fv;
        db += b[i] * gv;
    }
    da = wave_reduce_sum(da);
    db = wave_reduce_sum(db);
    int wid = tid >> 6, ln = tid & 63;
    if (ln == 0) { red[wid] = da; red[wid + 16] = db; }
    __syncthreads();
    if (tid == 0) {
        float DA = 0.f, DB = 0.f;
        int nw = blockDim.x >> 6;
        for (int w = 0; w < nw; w++) { DA += red[w]; DB += red[w + 16]; }
        out[0] = DA / sums[2] + DB / sums[3];
    }
}

extern "C" void kernel_launch(void* const* d_in, const int* in_sizes, int n_in,
                              void* d_out, int out_size, void* d_ws, size_t ws_size,
                              hipStream_t stream) {
    const float* a = (const float*)d_in[0];
    const float* x = (const float*)d_in[1];
    const float* b = (const float*)d_in[2];
    const float* y = (const float*)d_in[3];

    char* ws = (char*)d_ws;
    short8* xr = (short8*)ws;                        // 1 MB row-major
    short8* yr = (short8*)(ws + (1 << 20));          // 1 MB
    short8* xs = (short8*)(ws + (2 << 20));          // 1 MB stream layout
    short8* ys = (short8*)(ws + (3 << 20));          // 1 MB
    float* fp  = (float*)(ws + (4 << 20));
    float* x2  = fp;
    float* y2  = fp + NR;
    float* la2 = fp + 2 * NR;
    float* lb2 = fp + 3 * NR;
    float2* P   = (float2*)(fp + 4 * NR);
    float2* Pf  = P;                 // f-side partials [2][NR]
    float2* Pb  = P + 2 * NR;        // g-side partials [2][NR]
    float2* Pff = P + 4 * NR;        // final f partials
    float2* Pgf = P + 6 * NR;        // final g partials
    float* sums = (float*)(P + 8 * NR);

    sums_kernel<<<1, 1024, 0, stream>>>(a, b, sums);
    prep_kernel<<<(2 * NR * 8) / 256, 256, 0, stream>>>(x, y, a, b, sums,
                                                        xr, yr, xs, ys,
                                                        x2, y2, la2, lb2, Pb);

    for (int it = 0; it < N_ITERS; it++) {
        // f-update: rows = x-side (row-major), cols = y-side (stream)
        pass_kernel<<<256, 1024, 0, stream>>>(xr, ys, Pb, lb2, Pf);
        // g-update: rows = y-side, cols = x-side
        pass_kernel<<<256, 1024, 0, stream>>>(yr, xs, Pf, la2, Pb);
    }
    // final symmetric update from detached potentials
    pass_kernel<<<256, 1024, 0, stream>>>(xr, ys, Pb, lb2, Pff);
    pass_kernel<<<256, 1024, 0, stream>>>(yr, xs, Pf, la2, Pgf);

    reduce_kernel<<<1, 1024, 0, stream>>>(a, b, sums, x2, y2, Pff, Pgf, (float*)d_out);
}